// Round 7
// baseline (16718.311 us; speedup 1.0000x reference)
//
#include <hip/hip_runtime.h>
#include <cstdint>
#include <cstddef>

#define T_SEQ 4096
#define EMB_D 512
#define HDIM 512
#define G4 2048
#define NTAGS 24
#define START_TAG 22
#define STOP_TAG 23
#define NEGV -10000.0f
#define NBLK 32      // persistent LSTM blocks per direction
#define HSLICE 16    // hidden units per block
#define SENT 0xFFFFFFFFu   // -NaN bit pattern; finite math can't produce it
#define NTILES 4096  // 64 t-bands x 2 dirs x 32 j-tiles

// ---------------------------------------------------------------------------
// FUSED kernel. ROUND 7: R6's fusion concept kept, producer path fixed.
// R6 post-mortem: 14.8ms came from xg being written as 16.8M individual 4B
// agent-scope atomic stores (uncoalesced write-through at the coherence
// point; WRITE 200MB, FETCH 350MB) + a bad 512-thread staging layout
// (5.9e7 LDS conflicts). Fix:
//   - workers run the ORIGINAL 256-thread gemm tile body verbatim (bit-exact
//     accumulation order, proven staging layout, coalesced NORMAL cached
//     stores); threads 256-511 only join barriers.
//   - one __threadfence() per tile (device release: L2 writeback) bounds
//     visibility. Data-is-the-flag stays correct with normal stores: each
//     word is written once, so any non-SENT value a consumer's agent-scope
//     load sees IS the final value; the fence guarantees eventual visibility
//     (no stuck lines -> no deadlock).
//   - consumer side unchanged from R6 (per-thread h poll = R3; xg sentinel
//     check per leader per step; tile priority fwd t-asc / bwd t-desc).
// 192 worker CUs x ~7us/tile finish all 4096 tiles in ~150-300us; the
// recurrence consumes a t-band per ~96us -> GEMM fully hidden after ~10us.
// ---------------------------------------------------------------------------
__global__ __attribute__((amdgpu_waves_per_eu(2, 2))) __launch_bounds__(512)
void fused_kernel(
    const int* __restrict__ sent, const float* __restrict__ emb,
    const float* __restrict__ w_ih_f, const float* __restrict__ b_ih_f, const float* __restrict__ b_hh_f,
    const float* __restrict__ w_ih_b, const float* __restrict__ b_ih_b, const float* __restrict__ b_hh_b,
    const float* __restrict__ w_hh_f, const float* __restrict__ w_hh_b,
    const float* __restrict__ h0, const float* __restrict__ c0,
    uint32_t* __restrict__ xg,       // [2][T][G4] float bits, pre-set SENT
    uint32_t* __restrict__ h_hist,   // [2][T][HDIM] float bits, pre-set SENT
    int* __restrict__ claim,         // [8] per-XCD rank counters, pre-zeroed
    int* __restrict__ tilectr)       // [1] gemm tile queue head, pre-zeroed
{
    // 16 KB shared, dual-purpose: workers use As/Bs (2x 32x64 fp32 tiles);
    // participants use hbuf double-buffer (2 x 544 floats, 68-stride pad).
    __shared__ __attribute__((aligned(16))) float smem[4096];
    __shared__ int rank_s;
    __shared__ int g_s;

    uint32_t xcc;
    asm volatile("s_getreg_b32 %0, hwreg(HW_REG_XCC_ID)" : "=s"(xcc));
    xcc &= 7u;
    const int tid = threadIdx.x;    // 512

    if (tid == 0)
        rank_s = __hip_atomic_fetch_add(&claim[xcc], 1, __ATOMIC_RELAXED,
                                        __HIP_MEMORY_SCOPE_AGENT);
    __syncthreads();
    const int rank = rank_s;

    if (xcc >= 2) {
        // ---------------- GEMM worker (XCD2-7 only) ----------------
        // Original gemm_xg body: 256 compute threads, threads 256-511 join
        // barriers only. Bit-exact accumulation order (k ascending).
        float* As = smem;          // As[k][t] at smem[k*64 + t]
        float* Bs = smem + 2048;   // Bs[k][j]
        const int lrow = tid >> 2;          // 0..63  (tid<256)
        const int lk   = (tid & 3) * 8;     // 0,8,16,24
        const int ty   = tid >> 4;          // 0..15 (M)
        const int tx   = tid & 15;          // 0..15 (N)
        float* xgf = (float*)xg;
        for (;;) {
            if (tid == 0)
                g_s = __hip_atomic_fetch_add(tilectr, 1, __ATOMIC_RELAXED,
                                             __HIP_MEMORY_SCOPE_AGENT);
            __syncthreads();               // also orders As/Bs reuse vs g_s
            const int g = g_s;
            if (g >= NTILES) break;
            // priority decode: band tt serves fwd t-tile tt AND bwd 63-tt;
            // both directions' first-needed tiles are g = 0..63.
            const int tt  = g >> 6;
            const int dir = (g >> 5) & 1;
            const int jt  = g & 31;
            const int mt  = dir ? (63 - tt) : tt;
            const int m0 = mt * 64, n0 = jt * 64;
            const float* W  = dir ? w_ih_b : w_ih_f;
            const float* bi = dir ? b_ih_b : b_ih_f;
            const float* bh = dir ? b_hh_b : b_hh_f;
            const float* aptr = nullptr; const float* bptr = nullptr;
            float acc[4][4];
            if (tid < 256) {
                const int srow = sent[m0 + lrow];
                aptr = emb + (size_t)srow * EMB_D + lk;
                bptr = W   + (size_t)(n0 + lrow) * EMB_D + lk;
                #pragma unroll
                for (int i = 0; i < 4; ++i)
                    #pragma unroll
                    for (int j = 0; j < 4; ++j) acc[i][j] = 0.f;
            }
            for (int kk = 0; kk < EMB_D; kk += 32) {
                float4 a0, a1, b0, b1;
                if (tid < 256) {
                    a0 = *(const float4*)(aptr + kk);
                    a1 = *(const float4*)(aptr + kk + 4);
                    b0 = *(const float4*)(bptr + kk);
                    b1 = *(const float4*)(bptr + kk + 4);
                }
                __syncthreads();   // previous compute done before overwrite
                if (tid < 256) {
                    As[(lk+0)*64+lrow]=a0.x; As[(lk+1)*64+lrow]=a0.y;
                    As[(lk+2)*64+lrow]=a0.z; As[(lk+3)*64+lrow]=a0.w;
                    As[(lk+4)*64+lrow]=a1.x; As[(lk+5)*64+lrow]=a1.y;
                    As[(lk+6)*64+lrow]=a1.z; As[(lk+7)*64+lrow]=a1.w;
                    Bs[(lk+0)*64+lrow]=b0.x; Bs[(lk+1)*64+lrow]=b0.y;
                    Bs[(lk+2)*64+lrow]=b0.z; Bs[(lk+3)*64+lrow]=b0.w;
                    Bs[(lk+4)*64+lrow]=b1.x; Bs[(lk+5)*64+lrow]=b1.y;
                    Bs[(lk+6)*64+lrow]=b1.z; Bs[(lk+7)*64+lrow]=b1.w;
                }
                __syncthreads();
                if (tid < 256) {
                    #pragma unroll
                    for (int k = 0; k < 32; ++k) {
                        float4 av = *(const float4*)&As[k*64 + ty*4];
                        float4 bv = *(const float4*)&Bs[k*64 + tx*4];
                        acc[0][0]+=av.x*bv.x; acc[0][1]+=av.x*bv.y; acc[0][2]+=av.x*bv.z; acc[0][3]+=av.x*bv.w;
                        acc[1][0]+=av.y*bv.x; acc[1][1]+=av.y*bv.y; acc[1][2]+=av.y*bv.z; acc[1][3]+=av.y*bv.w;
                        acc[2][0]+=av.z*bv.x; acc[2][1]+=av.z*bv.y; acc[2][2]+=av.z*bv.z; acc[2][3]+=av.z*bv.w;
                        acc[3][0]+=av.w*bv.x; acc[3][1]+=av.w*bv.y; acc[3][2]+=av.w*bv.z; acc[3][3]+=av.w*bv.w;
                    }
                }
            }
            if (tid < 256) {
                #pragma unroll
                for (int i = 0; i < 4; ++i) {
                    const int t = m0 + ty*4 + i;
                    float* crow = xgf + ((size_t)dir*T_SEQ + t) * G4 + n0 + tx*4;
                    #pragma unroll
                    for (int j = 0; j < 4; ++j) {
                        const int jg = n0 + tx*4 + j;
                        crow[j] = acc[i][j] + bi[jg] + bh[jg];   // normal cached store
                    }
                }
            }
            // device-scope release: write back dirty L2 lines so the tile's
            // words reach the coherence point (consumers poll agent-scope).
            __threadfence();
        }
        return;
    }

    // ---------------- LSTM participant (exact R3 body + xg sentinel) ------
    if (rank >= NBLK) return;     // keep XCD0/1 free of worker traffic
    const int dir = (int)xcc;     // 0 or 1
    const int b = rank;

    const int q   = tid >> 6;       // wave 0..7
    const int l   = tid & 63;       // lane
    const int r   = l >> 3;         // row-in-wave 0..7
    const int i   = l & 7;          // segment index 0..7
    const int gate = r & 3;         // 0=i 1=f 2=g 3=o
    const int huo  = r >> 2;        // 0/1 -> hidden unit 2q+huo
    const int row  = gate * HDIM + b * HSLICE + 2*q + huo;   // global gate row

    // weights: lane dots h[64i .. 64i+63] against w_hh[row][64i..64i+63]
    const float* Wrow = (dir ? w_hh_b : w_hh_f) + (size_t)row * HDIM + i * 64;
    float w[64];
    #pragma unroll
    for (int j = 0; j < 16; ++j) {
        float4 v = ((const float4*)Wrow)[j];
        w[4*j+0]=v.x; w[4*j+1]=v.y; w[4*j+2]=v.z; w[4*j+3]=v.w;
    }
    // Pin weights in VGPRs (R5: 7.17->6.63ms; budget 256 via waves_per_eu(2,2))
    #pragma unroll
    for (int ii = 0; ii < 64; ++ii) asm volatile("" : "+v"(w[ii]));

    // c state: lanes 0 and 32 hold c for hidden units 2q and 2q+1
    float c = 0.f;
    if (i == 0 && gate == 0)   // l==0 or l==32
        c = c0[dir*HDIM + b*HSLICE + 2*q + huo];

    const uint32_t* xgu = xg + (size_t)dir * T_SEQ * G4;
    uint32_t* hh = h_hist + (size_t)dir * T_SEQ * HDIM;
    const bool leader = (i == 0);

    // preload xg for idx=0 (leaders); band 0 is ready within ~10us
    uint32_t xu_cur = 0;
    const uint32_t* xp_cur = xgu;
    if (leader) {
        const int t0 = dir ? (T_SEQ - 1) : 0;
        xp_cur = xgu + (size_t)t0 * G4 + row;
        xu_cur = __hip_atomic_load(xp_cur, __ATOMIC_RELAXED, __HIP_MEMORY_SCOPE_AGENT);
    }

    for (int idx = 0; idx < T_SEQ; ++idx) {
        const int t = dir ? (T_SEQ - 1 - idx) : idx;
        float* hb = smem + (idx & 1) * 544;   // padded double buffer

        // -- poll h[t-1][tid] (one value per thread, data-is-the-flag) --
        float hv;
        if (idx == 0) {
            hv = h0[dir*HDIM + tid];
        } else {
            const int tprev = dir ? (t + 1) : (t - 1);
            const uint32_t* wp = hh + (size_t)tprev*HDIM + tid;
            uint32_t u;
            do {
                u = __hip_atomic_load(wp, __ATOMIC_RELAXED, __HIP_MEMORY_SCOPE_AGENT);
            } while (u == SENT);
            union { uint32_t uu; float f; } cv; cv.uu = u;
            hv = cv.f;
        }
        hb[q*68 + l] = hv;
        __syncthreads();                       // B1: h published in LDS

        // resolve this step's xg (spins only if GEMM hasn't produced it yet;
        // never taken after the first few steps)
        float xv_cur = 0.f;
        if (leader) {
            while (xu_cur == SENT)
                xu_cur = __hip_atomic_load(xp_cur, __ATOMIC_RELAXED, __HIP_MEMORY_SCOPE_AGENT);
            xv_cur = __uint_as_float(xu_cur);
        }
        // prefetch next step's xg (checked at next step's resolve)
        if (leader && idx + 1 < T_SEQ) {
            const int tn = dir ? (t - 1) : (t + 1);
            xp_cur = xgu + (size_t)tn * G4 + row;
            xu_cur = __hip_atomic_load(xp_cur, __ATOMIC_RELAXED, __HIP_MEMORY_SCOPE_AGENT);
        }

        // -- per-lane partial: identical FMA chain to R3 --
        const float4* hb4 = (const float4*)&hb[i*68];
        float s = 0.f;
        #pragma unroll
        for (int j = 0; j < 16; ++j) {
            float4 hvv = hb4[j];               // broadcast across 8 lanes
            s += w[4*j+0]*hvv.x + w[4*j+1]*hvv.y + w[4*j+2]*hvv.z + w[4*j+3]*hvv.w;
        }

        // -- left-fold gather: g = xv + P0 + P1 + ... + P7 (R3 order) --
        const int gbase = l & ~7;              // leader lane of this row group
        float g = xv_cur + s;                  // leader: xv + P0
        #pragma unroll
        for (int j = 1; j < 8; ++j) {
            float pj = __shfl(s, gbase + j);
            g += pj;
        }
        // only leaders' g is consumed below.

        // -- activation (same formulas) --
        float act = (gate == 2) ? tanhf(g) : 1.f/(1.f + expf(-g));

        // -- gather 4 gates for this wave's 2 hidden units --
        const int base = l & 32;               // 0 for hu 2q, 32 for hu 2q+1
        float iv = __shfl(act, base + 0);
        float fg = __shfl(act, base + 8);
        float gv = __shfl(act, base + 16);
        float ov = __shfl(act, base + 24);

        if ((l & 31) == 0) {                   // lanes 0 and 32
            c = fg*c + iv*gv;
            union { float f; uint32_t u; } hbv; hbv.f = ov * tanhf(c);
            __hip_atomic_store(hh + (size_t)t*HDIM + b*HSLICE + 2*q + (l>>5), hbv.u,
                               __ATOMIC_RELAXED, __HIP_MEMORY_SCOPE_AGENT);
        }
        // hbuf[p] rewrite at idx+2 gated by B1(idx+1); readers of hbuf[p] at
        // idx finished before arriving there. One barrier per step.
    }
}

// ---------------------------------------------------------------------------
// 3) feats[t][tag] = b_tag[tag] + [hf|hb] . w_tag[tag]
// ---------------------------------------------------------------------------
__global__ __launch_bounds__(256) void feats_kernel(
    const float* __restrict__ h_hist, const float* __restrict__ w_tag,
    const float* __restrict__ b_tag, float* __restrict__ feats)
{
    const int t = blockIdx.x;
    const int tid = threadIdx.x;
    __shared__ __attribute__((aligned(16))) float h[1024];
    __shared__ float partl[192];
    for (int i = tid; i < 512; i += 256) {
        h[i]     = h_hist[(size_t)t*HDIM + i];
        h[512+i] = h_hist[(size_t)T_SEQ*HDIM + (size_t)t*HDIM + i];
    }
    __syncthreads();
    if (tid < 192) {
        const int tag = tid >> 3, p = tid & 7;
        const float* wr = w_tag + (size_t)tag*1024 + p*128;
        const float* hp = h + p*128;
        float s = 0.f;
        #pragma unroll 8
        for (int j = 0; j < 128; ++j) s += wr[j]*hp[j];
        partl[tid] = s;
    }
    __syncthreads();
    if (tid < NTAGS) {
        float s = b_tag[tid];
        #pragma unroll
        for (int p = 0; p < 8; ++p) s += partl[tid*8+p];
        feats[(size_t)t*NTAGS + tid] = s;
    }
}

// ---------------------------------------------------------------------------
// 4) Viterbi forward: single wave, LDS broadcast. Strict > keeps FIRST argmax.
// ---------------------------------------------------------------------------
__global__ void viterbi_fwd_kernel(
    const float* __restrict__ feats, const float* __restrict__ trans,
    float* __restrict__ d_out, unsigned char* __restrict__ bp,
    int* __restrict__ best_tag)
{
    const int lane = threadIdx.x;       // 64 threads = 1 wave
    const bool act = lane < NTAGS;
    float tr[NTAGS];
    #pragma unroll
    for (int p = 0; p < NTAGS; ++p)
        tr[p] = act ? trans[lane*NTAGS + p] : NEGV;

    float fv = (lane == START_TAG) ? 0.f : NEGV;
    __shared__ float fvs[NTAGS];
    __shared__ float term[NTAGS];

    float ftn = act ? feats[lane] : 0.f;   // prefetch t=0
    for (int t = 0; t < T_SEQ; ++t) {
        if (act) fvs[lane] = fv;
        __syncthreads();
        float ft = ftn;
        if (act && t + 1 < T_SEQ) ftn = feats[(size_t)(t+1)*NTAGS + lane];
        float bestv = -3.4e38f;
        int argp = 0;
        #pragma unroll
        for (int p = 0; p < NTAGS; ++p) {
            float sc = tr[p] + fvs[p];
            if (sc > bestv) { bestv = sc; argp = p; }
        }
        __syncthreads();   // reads done before next iteration's write
        fv = bestv + ft;
        if (act) bp[(size_t)t*NTAGS + lane] = (unsigned char)argp;
    }
    if (act) { fv += trans[STOP_TAG*NTAGS + lane]; term[lane] = fv; }
    __syncthreads();
    if (lane == 0) {
        float bv = term[0]; int bi = 0;
        #pragma unroll
        for (int p = 1; p < NTAGS; ++p) if (term[p] > bv) { bv = term[p]; bi = p; }
        d_out[0] = bv;
        *best_tag = bi;
    }
}

// ---------------------------------------------------------------------------
// 5) Hierarchical backtrack
// ---------------------------------------------------------------------------
__global__ void bt_compose_kernel(const unsigned char* __restrict__ bp,
                                  unsigned char* __restrict__ segmap)
{
    const int s = blockIdx.x;
    const int tid = threadIdx.x;   // 64
    __shared__ __attribute__((aligned(16))) unsigned char lbp[64*NTAGS];
    const uint32_t* src = (const uint32_t*)(bp + (size_t)s * 64 * NTAGS);
    uint32_t* dst = (uint32_t*)lbp;
    #pragma unroll
    for (int i = 0; i < 6; ++i) dst[tid + 64*i] = src[tid + 64*i];
    __syncthreads();
    if (tid < NTAGS) {
        int m = tid;
        for (int tt = 63; tt >= 0; --tt) m = lbp[tt*NTAGS + m];
        segmap[s*NTAGS + tid] = (unsigned char)m;
    }
}

__global__ void bt_final_kernel(const unsigned char* __restrict__ segmap,
                                const int* __restrict__ best_tag,
                                int* __restrict__ end_tags)
{
    if (threadIdx.x == 0) {
        int tag = *best_tag;
        end_tags[63] = tag;
        for (int s = 63; s >= 1; --s) {
            tag = segmap[s*NTAGS + tag];
            end_tags[s-1] = tag;
        }
    }
}

__global__ void bt_write_kernel(const unsigned char* __restrict__ bp,
                                const int* __restrict__ end_tags,
                                float* __restrict__ out_path)
{
    const int s = blockIdx.x;
    const int tid = threadIdx.x;   // 64
    __shared__ __attribute__((aligned(16))) unsigned char lbp[64*NTAGS];
    const uint32_t* src = (const uint32_t*)(bp + (size_t)s * 64 * NTAGS);
    uint32_t* dst = (uint32_t*)lbp;
    #pragma unroll
    for (int i = 0; i < 6; ++i) dst[tid + 64*i] = src[tid + 64*i];
    __syncthreads();
    if (tid == 0) {
        int tag = end_tags[s];
        out_path[s*64 + 63] = (float)tag;
        for (int tt = 63; tt >= 1; --tt) {
            tag = lbp[tt*NTAGS + tag];
            out_path[s*64 + tt - 1] = (float)tag;
        }
    }
}

// ---------------------------------------------------------------------------
extern "C" void kernel_launch(void* const* d_in, const int* in_sizes, int n_in,
                              void* d_out, int out_size, void* d_ws, size_t ws_size,
                              hipStream_t stream)
{
    const int*   sent   = (const int*)d_in[0];
    const float* emb    = (const float*)d_in[1];
    const float* w_ih_f = (const float*)d_in[2];
    const float* w_hh_f = (const float*)d_in[3];
    const float* b_ih_f = (const float*)d_in[4];
    const float* b_hh_f = (const float*)d_in[5];
    const float* w_ih_b = (const float*)d_in[6];
    const float* w_hh_b = (const float*)d_in[7];
    const float* b_ih_b = (const float*)d_in[8];
    const float* b_hh_b = (const float*)d_in[9];
    const float* w_tag  = (const float*)d_in[10];
    const float* b_tag  = (const float*)d_in[11];
    const float* trans  = (const float*)d_in[12];
    const float* h0     = (const float*)d_in[13];
    const float* c0     = (const float*)d_in[14];
    float* out = (float*)d_out;

    char* ws = (char*)d_ws;
    size_t off = 0;
    auto alloc = [&](size_t bytes) {
        char* p = ws + off; off += (bytes + 255) & ~(size_t)255; return p;
    };
    uint32_t* xg     = (uint32_t*)alloc((size_t)2*T_SEQ*G4*sizeof(float));   // 64 MB
    uint32_t* h_hist = (uint32_t*)alloc((size_t)2*T_SEQ*HDIM*sizeof(float)); // 16 MB
    float* feats   = (float*)alloc((size_t)T_SEQ*NTAGS*sizeof(float));
    unsigned char* bp     = (unsigned char*)alloc((size_t)T_SEQ*NTAGS);
    unsigned char* segmap = (unsigned char*)alloc(64*NTAGS);
    int* best_tag = (int*)alloc(sizeof(int));
    int* end_tags = (int*)alloc(64*sizeof(int));
    int* claim    = (int*)alloc(8*sizeof(int));
    int* tilectr  = (int*)alloc(sizeof(int));

    if (off > ws_size) {   // diagnostic sentinel: workspace too small
        hipMemsetAsync(d_out, 0xFF, 4, stream);
        return;
    }

    // data-is-the-flag sentinels (harness poison is 0xAA)
    hipMemsetAsync(xg,     0xFF, (size_t)2*T_SEQ*G4*sizeof(float), stream);
    hipMemsetAsync(h_hist, 0xFF, (size_t)2*T_SEQ*HDIM*sizeof(float), stream);
    hipMemsetAsync(claim, 0, 8*sizeof(int), stream);
    hipMemsetAsync(tilectr, 0, sizeof(int), stream);

    fused_kernel<<<512, 512, 0, stream>>>(
        sent, emb,
        w_ih_f, b_ih_f, b_hh_f, w_ih_b, b_ih_b, b_hh_b,
        w_hh_f, w_hh_b, h0, c0,
        xg, h_hist, claim, tilectr);
    feats_kernel<<<T_SEQ, 256, 0, stream>>>((const float*)h_hist, w_tag, b_tag, feats);
    viterbi_fwd_kernel<<<1, 64, 0, stream>>>(feats, trans, out, bp, best_tag);
    bt_compose_kernel<<<64, 64, 0, stream>>>(bp, segmap);
    bt_final_kernel<<<1, 64, 0, stream>>>(segmap, best_tag, end_tags);
    bt_write_kernel<<<64, 64, 0, stream>>>(bp, end_tags, out + 1);
}

// Round 8
// 9143.925 us; speedup vs baseline: 1.8284x; 1.8284x over previous
//
#include <hip/hip_runtime.h>
#include <cstdint>
#include <cstddef>

#define T_SEQ 4096
#define EMB_D 512
#define HDIM 512
#define G4 2048
#define NTAGS 24
#define START_TAG 22
#define STOP_TAG 23
#define NEGV -10000.0f
#define NBLK 32      // persistent LSTM blocks per direction
#define HSLICE 16    // hidden units per block
#define SENT 0xFFFFFFFFu   // h_hist sentinel; |h|<1 can never equal this
#define NTILES 4096  // 64 t-bands x 2 dirs x 32 j-tiles

// ---------------------------------------------------------------------------
// FUSED kernel. ROUND 8: BAND-FLAG PROTOCOL, R3-EXACT INNER LOOP.
// R6 vs R7 isolated the fused slowdown: producer path changes (atomic stores
// -> cached stores+fence) moved WRITE 200->131MB but duration was IDENTICAL
// (14.79 vs 14.75ms) => the 2.4x recurrence slowdown lives in the CONSUMER
// path: per-step agent-scope xg atomic loads + sentinel-resolve loop (the
// only participant-side difference from R3's 6.1ms). Fix: xg consumption
// returns to R3's normal cached float loads; readiness moves to band
// granularity (once per 64 steps):
//   worker:      tile stores -> __syncthreads (vmcnt drained, stores in L2)
//                -> tid0 fetch_add(readyctr[dir][mt], RELEASE, AGENT)
//                (release = L2 writeback: stores reach coherence point)
//   participant: when prefetch crosses into a new t-tile, all threads spin
//                on readyctr==32 with ACQUIRE/AGENT loads (acquire = L1/L2
//                invalidate -> subsequent normal loads fetch fresh; xg has
//                zero reuse so invalidation costs nothing). Wave-uniform,
//                1 iteration in steady state, 64x per recurrence.
// xg sentinel memset is gone. If this STILL runs ~14ms with a bit-identical
// R3 inner loop, the cause is worker coexistence -> revert fusion next round.
// ---------------------------------------------------------------------------
__global__ __attribute__((amdgpu_waves_per_eu(2, 2))) __launch_bounds__(512)
void fused_kernel(
    const int* __restrict__ sent, const float* __restrict__ emb,
    const float* __restrict__ w_ih_f, const float* __restrict__ b_ih_f, const float* __restrict__ b_hh_f,
    const float* __restrict__ w_ih_b, const float* __restrict__ b_ih_b, const float* __restrict__ b_hh_b,
    const float* __restrict__ w_hh_f, const float* __restrict__ w_hh_b,
    const float* __restrict__ h0, const float* __restrict__ c0,
    float* __restrict__ xg,          // [2][T][G4] plain floats (no sentinel)
    uint32_t* __restrict__ h_hist,   // [2][T][HDIM] float bits, pre-set SENT
    int* __restrict__ claim,         // [8] per-XCD rank counters, pre-zeroed
    int* __restrict__ tilectr,       // [1] gemm tile queue head, pre-zeroed
    int* __restrict__ readyctr)      // [2*64] per (dir,t-tile) done count, pre-zeroed
{
    // 16 KB shared, dual-purpose: workers use As/Bs (2x 32x64 fp32 tiles);
    // participants use hbuf double-buffer (2 x 544 floats, 68-stride pad).
    __shared__ __attribute__((aligned(16))) float smem[4096];
    __shared__ int rank_s;
    __shared__ int g_s;

    uint32_t xcc;
    asm volatile("s_getreg_b32 %0, hwreg(HW_REG_XCC_ID)" : "=s"(xcc));
    xcc &= 7u;
    const int tid = threadIdx.x;    // 512

    if (tid == 0)
        rank_s = __hip_atomic_fetch_add(&claim[xcc], 1, __ATOMIC_RELAXED,
                                        __HIP_MEMORY_SCOPE_AGENT);
    __syncthreads();
    const int rank = rank_s;

    if (xcc >= 2) {
        // ---------------- GEMM worker (XCD2-7 only) ----------------
        // Original gemm_xg body: 256 compute threads, threads 256-511 join
        // barriers only. Bit-exact accumulation order (k ascending).
        float* As = smem;          // As[k][t] at smem[k*64 + t]
        float* Bs = smem + 2048;   // Bs[k][j]
        const int lrow = tid >> 2;          // 0..63  (tid<256)
        const int lk   = (tid & 3) * 8;     // 0,8,16,24
        const int ty   = tid >> 4;          // 0..15 (M)
        const int tx   = tid & 15;          // 0..15 (N)
        for (;;) {
            if (tid == 0)
                g_s = __hip_atomic_fetch_add(tilectr, 1, __ATOMIC_RELAXED,
                                             __HIP_MEMORY_SCOPE_AGENT);
            __syncthreads();
            const int g = g_s;
            if (g >= NTILES) break;
            // priority decode: band tt serves fwd t-tile tt AND bwd 63-tt;
            // both directions' first-needed tiles are g = 0..63.
            const int tt  = g >> 6;
            const int dir = (g >> 5) & 1;
            const int jt  = g & 31;
            const int mt  = dir ? (63 - tt) : tt;
            const int m0 = mt * 64, n0 = jt * 64;
            const float* W  = dir ? w_ih_b : w_ih_f;
            const float* bi = dir ? b_ih_b : b_ih_f;
            const float* bh = dir ? b_hh_b : b_hh_f;
            const float* aptr = nullptr; const float* bptr = nullptr;
            float acc[4][4];
            if (tid < 256) {
                const int srow = sent[m0 + lrow];
                aptr = emb + (size_t)srow * EMB_D + lk;
                bptr = W   + (size_t)(n0 + lrow) * EMB_D + lk;
                #pragma unroll
                for (int i = 0; i < 4; ++i)
                    #pragma unroll
                    for (int j = 0; j < 4; ++j) acc[i][j] = 0.f;
            }
            for (int kk = 0; kk < EMB_D; kk += 32) {
                float4 a0, a1, b0, b1;
                if (tid < 256) {
                    a0 = *(const float4*)(aptr + kk);
                    a1 = *(const float4*)(aptr + kk + 4);
                    b0 = *(const float4*)(bptr + kk);
                    b1 = *(const float4*)(bptr + kk + 4);
                }
                __syncthreads();   // previous compute done before overwrite
                if (tid < 256) {
                    As[(lk+0)*64+lrow]=a0.x; As[(lk+1)*64+lrow]=a0.y;
                    As[(lk+2)*64+lrow]=a0.z; As[(lk+3)*64+lrow]=a0.w;
                    As[(lk+4)*64+lrow]=a1.x; As[(lk+5)*64+lrow]=a1.y;
                    As[(lk+6)*64+lrow]=a1.z; As[(lk+7)*64+lrow]=a1.w;
                    Bs[(lk+0)*64+lrow]=b0.x; Bs[(lk+1)*64+lrow]=b0.y;
                    Bs[(lk+2)*64+lrow]=b0.z; Bs[(lk+3)*64+lrow]=b0.w;
                    Bs[(lk+4)*64+lrow]=b1.x; Bs[(lk+5)*64+lrow]=b1.y;
                    Bs[(lk+6)*64+lrow]=b1.z; Bs[(lk+7)*64+lrow]=b1.w;
                }
                __syncthreads();
                if (tid < 256) {
                    #pragma unroll
                    for (int k = 0; k < 32; ++k) {
                        float4 av = *(const float4*)&As[k*64 + ty*4];
                        float4 bv = *(const float4*)&Bs[k*64 + tx*4];
                        acc[0][0]+=av.x*bv.x; acc[0][1]+=av.x*bv.y; acc[0][2]+=av.x*bv.z; acc[0][3]+=av.x*bv.w;
                        acc[1][0]+=av.y*bv.x; acc[1][1]+=av.y*bv.y; acc[1][2]+=av.y*bv.z; acc[1][3]+=av.y*bv.w;
                        acc[2][0]+=av.z*bv.x; acc[2][1]+=av.z*bv.y; acc[2][2]+=av.z*bv.z; acc[2][3]+=av.z*bv.w;
                        acc[3][0]+=av.w*bv.x; acc[3][1]+=av.w*bv.y; acc[3][2]+=av.w*bv.z; acc[3][3]+=av.w*bv.w;
                    }
                }
            }
            if (tid < 256) {
                #pragma unroll
                for (int i = 0; i < 4; ++i) {
                    const int t = m0 + ty*4 + i;
                    float* crow = xg + ((size_t)dir*T_SEQ + t) * G4 + n0 + tx*4;
                    #pragma unroll
                    for (int j = 0; j < 4; ++j) {
                        const int jg = n0 + tx*4 + j;
                        crow[j] = acc[i][j] + bi[jg] + bh[jg];   // normal cached store
                    }
                }
            }
            // all threads' stores drained (s_waitcnt before barrier) and in
            // this XCD's L2; tid0's agent-release then writes back L2 so the
            // tile's data reaches the coherence point before the count bumps.
            __syncthreads();
            if (tid == 0)
                __hip_atomic_fetch_add(&readyctr[dir*64 + mt], 1,
                                       __ATOMIC_RELEASE, __HIP_MEMORY_SCOPE_AGENT);
        }
        return;
    }

    // ---------------- LSTM participant (EXACT R3 body + band gate) --------
    if (rank >= NBLK) return;     // keep XCD0/1 free of worker traffic
    const int dir = (int)xcc;     // 0 or 1
    const int b = rank;

    const int q   = tid >> 6;       // wave 0..7
    const int l   = tid & 63;       // lane
    const int r   = l >> 3;         // row-in-wave 0..7
    const int i   = l & 7;          // segment index 0..7
    const int gate = r & 3;         // 0=i 1=f 2=g 3=o
    const int huo  = r >> 2;        // 0/1 -> hidden unit 2q+huo
    const int row  = gate * HDIM + b * HSLICE + 2*q + huo;   // global gate row

    // weights: lane dots h[64i .. 64i+63] against w_hh[row][64i..64i+63]
    const float* Wrow = (dir ? w_hh_b : w_hh_f) + (size_t)row * HDIM + i * 64;
    float w[64];
    #pragma unroll
    for (int j = 0; j < 16; ++j) {
        float4 v = ((const float4*)Wrow)[j];
        w[4*j+0]=v.x; w[4*j+1]=v.y; w[4*j+2]=v.z; w[4*j+3]=v.w;
    }
    // Pin weights in VGPRs (R5: 7.17->6.63ms; budget 256 via waves_per_eu(2,2))
    #pragma unroll
    for (int ii = 0; ii < 64; ++ii) asm volatile("" : "+v"(w[ii]));

    // c state: lanes 0 and 32 hold c for hidden units 2q and 2q+1
    float c = 0.f;
    if (i == 0 && gate == 0)   // l==0 or l==32
        c = c0[dir*HDIM + b*HSLICE + 2*q + huo];

    const float* xgd = xg + (size_t)dir * T_SEQ * G4;
    uint32_t* hh = h_hist + (size_t)dir * T_SEQ * HDIM;
    const bool leader = (i == 0);

    // band gate state: bands visited monotonically (fwd 0->63, bwd 63->0)
    int checked = -1;
    const int* rc = readyctr + dir*64;

    // initial band gate + xg preload for idx=0 (normal cached loads; the
    // ACQUIRE spin invalidates L1/L2 so fresh worker data is fetched)
    {
        const int t0 = dir ? (T_SEQ - 1) : 0;
        const int b0 = t0 >> 6;
        while (__hip_atomic_load(&rc[b0], __ATOMIC_ACQUIRE,
                                 __HIP_MEMORY_SCOPE_AGENT) < 32) {}
        checked = b0;
    }
    float xv_cur = 0.f;
    if (leader) {
        const int t0 = dir ? (T_SEQ - 1) : 0;
        xv_cur = xgd[(size_t)t0 * G4 + row];
    }

    for (int idx = 0; idx < T_SEQ; ++idx) {
        const int t = dir ? (T_SEQ - 1 - idx) : idx;
        float* hb = smem + (idx & 1) * 544;   // padded double buffer

        // -- poll h[t-1][tid] (one value per thread, data-is-the-flag) --
        float hv;
        if (idx == 0) {
            hv = h0[dir*HDIM + tid];
        } else {
            const int tprev = dir ? (t + 1) : (t - 1);
            const uint32_t* wp = hh + (size_t)tprev*HDIM + tid;
            uint32_t u;
            do {
                u = __hip_atomic_load(wp, __ATOMIC_RELAXED, __HIP_MEMORY_SCOPE_AGENT);
            } while (u == SENT);
            union { uint32_t uu; float f; } cv; cv.uu = u;
            hv = cv.f;
        }
        hb[q*68 + l] = hv;
        __syncthreads();                       // B1: h published in LDS

        // prefetch next step's xg (normal cached load, R3-exact), gated once
        // per 64 steps when tn crosses into a new t-tile (wave-uniform).
        float xv_nxt = 0.f;
        if (idx + 1 < T_SEQ) {
            const int tn = dir ? (t - 1) : (t + 1);
            const int bn = tn >> 6;
            if (bn != checked) {
                while (__hip_atomic_load(&rc[bn], __ATOMIC_ACQUIRE,
                                         __HIP_MEMORY_SCOPE_AGENT) < 32) {}
                checked = bn;
            }
            if (leader)
                xv_nxt = xgd[(size_t)tn * G4 + row];
        }

        // -- per-lane partial: identical FMA chain to R3 --
        const float4* hb4 = (const float4*)&hb[i*68];
        float s = 0.f;
        #pragma unroll
        for (int j = 0; j < 16; ++j) {
            float4 hvv = hb4[j];               // broadcast across 8 lanes
            s += w[4*j+0]*hvv.x + w[4*j+1]*hvv.y + w[4*j+2]*hvv.z + w[4*j+3]*hvv.w;
        }

        // -- left-fold gather: g = xv + P0 + P1 + ... + P7 (R3 order) --
        const int gbase = l & ~7;              // leader lane of this row group
        float g = xv_cur + s;                  // leader: xv + P0
        #pragma unroll
        for (int j = 1; j < 8; ++j) {
            float pj = __shfl(s, gbase + j);
            g += pj;
        }
        // only leaders' g is consumed below.

        // -- activation (same formulas) --
        float act = (gate == 2) ? tanhf(g) : 1.f/(1.f + expf(-g));

        // -- gather 4 gates for this wave's 2 hidden units --
        const int base = l & 32;               // 0 for hu 2q, 32 for hu 2q+1
        float iv = __shfl(act, base + 0);
        float fg = __shfl(act, base + 8);
        float gv = __shfl(act, base + 16);
        float ov = __shfl(act, base + 24);

        if ((l & 31) == 0) {                   // lanes 0 and 32
            c = fg*c + iv*gv;
            union { float f; uint32_t u; } hbv; hbv.f = ov * tanhf(c);
            __hip_atomic_store(hh + (size_t)t*HDIM + b*HSLICE + 2*q + (l>>5), hbv.u,
                               __ATOMIC_RELAXED, __HIP_MEMORY_SCOPE_AGENT);
        }
        xv_cur = xv_nxt;
        // hbuf[p] rewrite at idx+2 gated by B1(idx+1); readers of hbuf[p] at
        // idx finished before arriving there. One barrier per step.
    }
}

// ---------------------------------------------------------------------------
// 3) feats[t][tag] = b_tag[tag] + [hf|hb] . w_tag[tag]
// ---------------------------------------------------------------------------
__global__ __launch_bounds__(256) void feats_kernel(
    const float* __restrict__ h_hist, const float* __restrict__ w_tag,
    const float* __restrict__ b_tag, float* __restrict__ feats)
{
    const int t = blockIdx.x;
    const int tid = threadIdx.x;
    __shared__ __attribute__((aligned(16))) float h[1024];
    __shared__ float partl[192];
    for (int i = tid; i < 512; i += 256) {
        h[i]     = h_hist[(size_t)t*HDIM + i];
        h[512+i] = h_hist[(size_t)T_SEQ*HDIM + (size_t)t*HDIM + i];
    }
    __syncthreads();
    if (tid < 192) {
        const int tag = tid >> 3, p = tid & 7;
        const float* wr = w_tag + (size_t)tag*1024 + p*128;
        const float* hp = h + p*128;
        float s = 0.f;
        #pragma unroll 8
        for (int j = 0; j < 128; ++j) s += wr[j]*hp[j];
        partl[tid] = s;
    }
    __syncthreads();
    if (tid < NTAGS) {
        float s = b_tag[tid];
        #pragma unroll
        for (int p = 0; p < 8; ++p) s += partl[tid*8+p];
        feats[(size_t)t*NTAGS + tid] = s;
    }
}

// ---------------------------------------------------------------------------
// 4) Viterbi forward: single wave, LDS broadcast. Strict > keeps FIRST argmax.
// ---------------------------------------------------------------------------
__global__ void viterbi_fwd_kernel(
    const float* __restrict__ feats, const float* __restrict__ trans,
    float* __restrict__ d_out, unsigned char* __restrict__ bp,
    int* __restrict__ best_tag)
{
    const int lane = threadIdx.x;       // 64 threads = 1 wave
    const bool act = lane < NTAGS;
    float tr[NTAGS];
    #pragma unroll
    for (int p = 0; p < NTAGS; ++p)
        tr[p] = act ? trans[lane*NTAGS + p] : NEGV;

    float fv = (lane == START_TAG) ? 0.f : NEGV;
    __shared__ float fvs[NTAGS];
    __shared__ float term[NTAGS];

    float ftn = act ? feats[lane] : 0.f;   // prefetch t=0
    for (int t = 0; t < T_SEQ; ++t) {
        if (act) fvs[lane] = fv;
        __syncthreads();
        float ft = ftn;
        if (act && t + 1 < T_SEQ) ftn = feats[(size_t)(t+1)*NTAGS + lane];
        float bestv = -3.4e38f;
        int argp = 0;
        #pragma unroll
        for (int p = 0; p < NTAGS; ++p) {
            float sc = tr[p] + fvs[p];
            if (sc > bestv) { bestv = sc; argp = p; }
        }
        __syncthreads();   // reads done before next iteration's write
        fv = bestv + ft;
        if (act) bp[(size_t)t*NTAGS + lane] = (unsigned char)argp;
    }
    if (act) { fv += trans[STOP_TAG*NTAGS + lane]; term[lane] = fv; }
    __syncthreads();
    if (lane == 0) {
        float bv = term[0]; int bi = 0;
        #pragma unroll
        for (int p = 1; p < NTAGS; ++p) if (term[p] > bv) { bv = term[p]; bi = p; }
        d_out[0] = bv;
        *best_tag = bi;
    }
}

// ---------------------------------------------------------------------------
// 5) Hierarchical backtrack
// ---------------------------------------------------------------------------
__global__ void bt_compose_kernel(const unsigned char* __restrict__ bp,
                                  unsigned char* __restrict__ segmap)
{
    const int s = blockIdx.x;
    const int tid = threadIdx.x;   // 64
    __shared__ __attribute__((aligned(16))) unsigned char lbp[64*NTAGS];
    const uint32_t* src = (const uint32_t*)(bp + (size_t)s * 64 * NTAGS);
    uint32_t* dst = (uint32_t*)lbp;
    #pragma unroll
    for (int i = 0; i < 6; ++i) dst[tid + 64*i] = src[tid + 64*i];
    __syncthreads();
    if (tid < NTAGS) {
        int m = tid;
        for (int tt = 63; tt >= 0; --tt) m = lbp[tt*NTAGS + m];
        segmap[s*NTAGS + tid] = (unsigned char)m;
    }
}

__global__ void bt_final_kernel(const unsigned char* __restrict__ segmap,
                                const int* __restrict__ best_tag,
                                int* __restrict__ end_tags)
{
    if (threadIdx.x == 0) {
        int tag = *best_tag;
        end_tags[63] = tag;
        for (int s = 63; s >= 1; --s) {
            tag = segmap[s*NTAGS + tag];
            end_tags[s-1] = tag;
        }
    }
}

__global__ void bt_write_kernel(const unsigned char* __restrict__ bp,
                                const int* __restrict__ end_tags,
                                float* __restrict__ out_path)
{
    const int s = blockIdx.x;
    const int tid = threadIdx.x;   // 64
    __shared__ __attribute__((aligned(16))) unsigned char lbp[64*NTAGS];
    const uint32_t* src = (const uint32_t*)(bp + (size_t)s * 64 * NTAGS);
    uint32_t* dst = (uint32_t*)lbp;
    #pragma unroll
    for (int i = 0; i < 6; ++i) dst[tid + 64*i] = src[tid + 64*i];
    __syncthreads();
    if (tid == 0) {
        int tag = end_tags[s];
        out_path[s*64 + 63] = (float)tag;
        for (int tt = 63; tt >= 1; --tt) {
            tag = lbp[tt*NTAGS + tag];
            out_path[s*64 + tt - 1] = (float)tag;
        }
    }
}

// ---------------------------------------------------------------------------
extern "C" void kernel_launch(void* const* d_in, const int* in_sizes, int n_in,
                              void* d_out, int out_size, void* d_ws, size_t ws_size,
                              hipStream_t stream)
{
    const int*   sent   = (const int*)d_in[0];
    const float* emb    = (const float*)d_in[1];
    const float* w_ih_f = (const float*)d_in[2];
    const float* w_hh_f = (const float*)d_in[3];
    const float* b_ih_f = (const float*)d_in[4];
    const float* b_hh_f = (const float*)d_in[5];
    const float* w_ih_b = (const float*)d_in[6];
    const float* w_hh_b = (const float*)d_in[7];
    const float* b_ih_b = (const float*)d_in[8];
    const float* b_hh_b = (const float*)d_in[9];
    const float* w_tag  = (const float*)d_in[10];
    const float* b_tag  = (const float*)d_in[11];
    const float* trans  = (const float*)d_in[12];
    const float* h0     = (const float*)d_in[13];
    const float* c0     = (const float*)d_in[14];
    float* out = (float*)d_out;

    char* ws = (char*)d_ws;
    size_t off = 0;
    auto alloc = [&](size_t bytes) {
        char* p = ws + off; off += (bytes + 255) & ~(size_t)255; return p;
    };
    float* xg        = (float*)alloc((size_t)2*T_SEQ*G4*sizeof(float));      // 64 MB
    uint32_t* h_hist = (uint32_t*)alloc((size_t)2*T_SEQ*HDIM*sizeof(float)); // 16 MB
    float* feats   = (float*)alloc((size_t)T_SEQ*NTAGS*sizeof(float));
    unsigned char* bp     = (unsigned char*)alloc((size_t)T_SEQ*NTAGS);
    unsigned char* segmap = (unsigned char*)alloc(64*NTAGS);
    int* best_tag = (int*)alloc(sizeof(int));
    int* end_tags = (int*)alloc(64*sizeof(int));
    int* ctrl     = (int*)alloc(256*sizeof(int));   // claim[8] | tilectr[1] | readyctr[128]
    int* claim    = ctrl;
    int* tilectr  = ctrl + 8;
    int* readyctr = ctrl + 16;

    if (off > ws_size) {   // diagnostic sentinel: workspace too small
        hipMemsetAsync(d_out, 0xFF, 4, stream);
        return;
    }

    // h_hist = 0xFFFFFFFF sentinel (data-is-the-flag; harness poison is 0xAA).
    // xg needs NO memset: readiness is band-flag-gated, not sentinel-gated.
    hipMemsetAsync(h_hist, 0xFF, (size_t)2*T_SEQ*HDIM*sizeof(float), stream);
    hipMemsetAsync(ctrl, 0, 256*sizeof(int), stream);

    fused_kernel<<<512, 512, 0, stream>>>(
        sent, emb,
        w_ih_f, b_ih_f, b_hh_f, w_ih_b, b_ih_b, b_hh_b,
        w_hh_f, w_hh_b, h0, c0,
        xg, h_hist, claim, tilectr, readyctr);
    feats_kernel<<<T_SEQ, 256, 0, stream>>>((const float*)h_hist, w_tag, b_tag, feats);
    viterbi_fwd_kernel<<<1, 64, 0, stream>>>(feats, trans, out, bp, best_tag);
    bt_compose_kernel<<<64, 64, 0, stream>>>(bp, segmap);
    bt_final_kernel<<<1, 64, 0, stream>>>(segmap, best_tag, end_tags);
    bt_write_kernel<<<64, 64, 0, stream>>>(bp, end_tags, out + 1);
}

// Round 9
// 7728.156 us; speedup vs baseline: 2.1633x; 1.1832x over previous
//
#include <hip/hip_runtime.h>
#include <cstdint>
#include <cstddef>

#define T_SEQ 4096
#define EMB_D 512
#define HDIM 512
#define G4 2048
#define NTAGS 24
#define START_TAG 22
#define STOP_TAG 23
#define NEGV -10000.0f
#define NBLK 32      // persistent blocks per direction
#define HSLICE 16    // hidden units per block
#define SENT 0xFFFFFFFFu   // -NaN bit pattern; |h|<1 can never equal this

// ---------------------------------------------------------------------------
// 1) xg[dir][t][j] = dot(emb[sent[t]], w_ih[j]) + b_ih[j] + b_hh[j]
//    (split prologue kernel, ~280us at full chip; fusion abandoned in R8:
//     worker coexistence cost the recurrence ~1.1ms > the 280us it could save)
// ---------------------------------------------------------------------------
__global__ __launch_bounds__(256) void gemm_xg_kernel(
    const int* __restrict__ sent, const float* __restrict__ emb,
    const float* __restrict__ w_ih_f, const float* __restrict__ b_ih_f, const float* __restrict__ b_hh_f,
    const float* __restrict__ w_ih_b, const float* __restrict__ b_ih_b, const float* __restrict__ b_hh_b,
    float* __restrict__ xg)
{
    const int dir = blockIdx.z;
    const float* W  = dir ? w_ih_b : w_ih_f;
    const float* bi = dir ? b_ih_b : b_ih_f;
    const float* bh = dir ? b_hh_b : b_hh_f;
    const int m0 = blockIdx.y * 64;   // t
    const int n0 = blockIdx.x * 64;   // gate row j
    const int tid = threadIdx.x;

    __shared__ __attribute__((aligned(16))) float As[32][64];  // [k][t]
    __shared__ __attribute__((aligned(16))) float Bs[32][64];  // [k][j]

    const int lrow = tid >> 2;          // 0..63
    const int lk   = (tid & 3) * 8;     // 0,8,16,24

    const int srow = sent[m0 + lrow];
    const float* aptr = emb + (size_t)srow * EMB_D + lk;
    const float* bptr = W   + (size_t)(n0 + lrow) * EMB_D + lk;

    const int ty = tid >> 4;   // 0..15 (M)
    const int tx = tid & 15;   // 0..15 (N)

    float acc[4][4];
    #pragma unroll
    for (int i = 0; i < 4; ++i)
        #pragma unroll
        for (int j = 0; j < 4; ++j) acc[i][j] = 0.f;

    for (int kk = 0; kk < EMB_D; kk += 32) {
        float4 a0 = *(const float4*)(aptr + kk);
        float4 a1 = *(const float4*)(aptr + kk + 4);
        float4 b0 = *(const float4*)(bptr + kk);
        float4 b1 = *(const float4*)(bptr + kk + 4);
        __syncthreads();   // previous iteration's compute done before overwrite
        As[lk+0][lrow]=a0.x; As[lk+1][lrow]=a0.y; As[lk+2][lrow]=a0.z; As[lk+3][lrow]=a0.w;
        As[lk+4][lrow]=a1.x; As[lk+5][lrow]=a1.y; As[lk+6][lrow]=a1.z; As[lk+7][lrow]=a1.w;
        Bs[lk+0][lrow]=b0.x; Bs[lk+1][lrow]=b0.y; Bs[lk+2][lrow]=b0.z; Bs[lk+3][lrow]=b0.w;
        Bs[lk+4][lrow]=b1.x; Bs[lk+5][lrow]=b1.y; Bs[lk+6][lrow]=b1.z; Bs[lk+7][lrow]=b1.w;
        __syncthreads();
        #pragma unroll
        for (int k = 0; k < 32; ++k) {
            float4 av = *(const float4*)&As[k][ty*4];
            float4 bv = *(const float4*)&Bs[k][tx*4];
            acc[0][0]+=av.x*bv.x; acc[0][1]+=av.x*bv.y; acc[0][2]+=av.x*bv.z; acc[0][3]+=av.x*bv.w;
            acc[1][0]+=av.y*bv.x; acc[1][1]+=av.y*bv.y; acc[1][2]+=av.y*bv.z; acc[1][3]+=av.y*bv.w;
            acc[2][0]+=av.z*bv.x; acc[2][1]+=av.z*bv.y; acc[2][2]+=av.z*bv.z; acc[2][3]+=av.z*bv.w;
            acc[3][0]+=av.w*bv.x; acc[3][1]+=av.w*bv.y; acc[3][2]+=av.w*bv.z; acc[3][3]+=av.w*bv.w;
        }
    }
    #pragma unroll
    for (int i = 0; i < 4; ++i) {
        const int t = m0 + ty*4 + i;
        float* crow = xg + ((size_t)dir*T_SEQ + t) * G4 + n0 + tx*4;
        #pragma unroll
        for (int j = 0; j < 4; ++j) {
            const int jg = n0 + tx*4 + j;
            crow[j] = acc[i][j] + bi[jg] + bh[jg];
        }
    }
}

// ---------------------------------------------------------------------------
// 2) Bidirectional LSTM, XCD co-location — EXACT R3 (best measured: 6.10ms).
//    Symmetric row-split: wave q owns hidden units {2q,2q+1}; 8-lane group
//    per gate row; lane i dots h-segment i; left-fold shuffle gather
//    g = xv + P0 + ... + P7 (bit-exact vs original reduce order).
// ---------------------------------------------------------------------------
__global__ __attribute__((amdgpu_waves_per_eu(2, 2))) __launch_bounds__(512)
void bilstm_kernel(
    const float* __restrict__ w_hh_f, const float* __restrict__ w_hh_b,
    const float* __restrict__ h0, const float* __restrict__ c0,
    const float* __restrict__ xg,
    uint32_t* __restrict__ h_hist,   // [2][T][HDIM] float bits, pre-set SENT
    int* __restrict__ claim)         // [8] per-XCD rank counters, pre-zeroed
{
    uint32_t xcc;
    asm volatile("s_getreg_b32 %0, hwreg(HW_REG_XCC_ID)" : "=s"(xcc));
    xcc &= 7u;

    __shared__ int rank_s;
    if (threadIdx.x == 0)
        rank_s = __hip_atomic_fetch_add(&claim[xcc], 1, __ATOMIC_RELAXED,
                                        __HIP_MEMORY_SCOPE_AGENT);
    __syncthreads();
    const int rank = rank_s;

    int dir;
    if (xcc == 0) dir = 0;
    else if (xcc == 1) dir = 1;
    else return;
    if (rank >= NBLK) return;
    const int b = rank;

    const int tid = threadIdx.x;    // 512
    const int q   = tid >> 6;       // wave 0..7
    const int l   = tid & 63;       // lane
    const int r   = l >> 3;         // row-in-wave 0..7
    const int i   = l & 7;          // segment index 0..7
    const int gate = r & 3;         // 0=i 1=f 2=g 3=o
    const int huo  = r >> 2;        // 0/1 -> hidden unit 2q+huo
    const int row  = gate * HDIM + b * HSLICE + 2*q + huo;   // global gate row

    // weights: lane dots h[64i .. 64i+63] against w_hh[row][64i..64i+63]
    const float* Wrow = (dir ? w_hh_b : w_hh_f) + (size_t)row * HDIM + i * 64;
    float w[64];
    #pragma unroll
    for (int j = 0; j < 16; ++j) {
        float4 v = ((const float4*)Wrow)[j];
        w[4*j+0]=v.x; w[4*j+1]=v.y; w[4*j+2]=v.z; w[4*j+3]=v.w;
    }
    // Pin weights in VGPRs (R5: 7.17->6.63ms; budget 256 via waves_per_eu(2,2))
    #pragma unroll
    for (int ii = 0; ii < 64; ++ii) asm volatile("" : "+v"(w[ii]));

    // padded, double-buffered h staging: segment s at [buf][68*s .. 68*s+63]
    __shared__ __attribute__((aligned(16))) float hbuf[2][544];

    // c state: lanes 0 and 32 hold c for hidden units 2q and 2q+1
    float c = 0.f;
    if (i == 0 && gate == 0)   // l==0 or l==32
        c = c0[dir*HDIM + b*HSLICE + 2*q + huo];

    const float* xgd = xg + (size_t)dir * T_SEQ * G4;
    uint32_t* hh = h_hist + (size_t)dir * T_SEQ * HDIM;
    const bool leader = (i == 0);

    // preload xg for idx=0 (leader lanes only)
    float xv_cur = 0.f;
    if (leader) {
        const int t0 = dir ? (T_SEQ - 1) : 0;
        xv_cur = xgd[(size_t)t0 * G4 + row];
    }

    for (int idx = 0; idx < T_SEQ; ++idx) {
        const int t = dir ? (T_SEQ - 1 - idx) : idx;
        const int p = idx & 1;

        // -- poll h[t-1][tid] (one value per thread, data-is-the-flag) --
        float hv;
        if (idx == 0) {
            hv = h0[dir*HDIM + tid];
        } else {
            const int tprev = dir ? (t + 1) : (t - 1);
            const uint32_t* wp = hh + (size_t)tprev*HDIM + tid;
            uint32_t u;
            do {
                u = __hip_atomic_load(wp, __ATOMIC_RELAXED, __HIP_MEMORY_SCOPE_AGENT);
            } while (u == SENT);
            union { uint32_t uu; float f; } cv; cv.uu = u;
            hv = cv.f;
        }
        hbuf[p][q*68 + l] = hv;
        __syncthreads();                       // B1: h published in LDS

        // prefetch next step's xg (leaders); consumed after next B1
        float xv_nxt = 0.f;
        if (leader && idx + 1 < T_SEQ) {
            const int tn = dir ? (t - 1) : (t + 1);
            xv_nxt = xgd[(size_t)tn * G4 + row];
        }

        // -- per-lane partial: identical FMA chain to old part[i] --
        const float4* hb4 = (const float4*)&hbuf[p][i*68];
        float s = 0.f;
        #pragma unroll
        for (int j = 0; j < 16; ++j) {
            float4 hvv = hb4[j];               // broadcast across 8 lanes
            s += w[4*j+0]*hvv.x + w[4*j+1]*hvv.y + w[4*j+2]*hvv.z + w[4*j+3]*hvv.w;
        }

        // -- left-fold gather: g = xv + P0 + P1 + ... + P7 (old reduce order)
        const int gbase = l & ~7;              // leader lane of this row group
        float g = xv_cur + s;                  // leader: xv + P0 (s==P0 on leader)
        #pragma unroll
        for (int j = 1; j < 8; ++j) {
            float pj = __shfl(s, gbase + j);
            g += pj;
        }
        // only leaders' g is consumed below.

        // -- activation (leaders), same formulas as before --
        float act = (gate == 2) ? tanhf(g) : 1.f/(1.f + expf(-g));

        // -- gather 4 gates for this wave's 2 hidden units --
        const int base = l & 32;               // 0 for hu 2q, 32 for hu 2q+1
        float iv = __shfl(act, base + 0);
        float fg = __shfl(act, base + 8);
        float gv = __shfl(act, base + 16);
        float ov = __shfl(act, base + 24);

        if ((l & 31) == 0) {                   // lanes 0 and 32
            c = fg*c + iv*gv;
            union { float f; uint32_t u; } hb; hb.f = ov * tanhf(c);
            __hip_atomic_store(hh + (size_t)t*HDIM + b*HSLICE + 2*q + (l>>5), hb.u,
                               __ATOMIC_RELAXED, __HIP_MEMORY_SCOPE_AGENT);
        }
        xv_cur = xv_nxt;
        // hbuf rewrite hazard: next write targets hbuf[p^1]; earliest rewrite
        // of hbuf[p] is at idx+2, reachable only after B1(idx+1).
    }
}

// ---------------------------------------------------------------------------
// 3) feats[t][tag] = b_tag[tag] + [hf|hb] . w_tag[tag]
// ---------------------------------------------------------------------------
__global__ __launch_bounds__(256) void feats_kernel(
    const float* __restrict__ h_hist, const float* __restrict__ w_tag,
    const float* __restrict__ b_tag, float* __restrict__ feats)
{
    const int t = blockIdx.x;
    const int tid = threadIdx.x;
    __shared__ __attribute__((aligned(16))) float h[1024];
    __shared__ float partl[192];
    for (int i = tid; i < 512; i += 256) {
        h[i]     = h_hist[(size_t)t*HDIM + i];
        h[512+i] = h_hist[(size_t)T_SEQ*HDIM + (size_t)t*HDIM + i];
    }
    __syncthreads();
    if (tid < 192) {
        const int tag = tid >> 3, p = tid & 7;
        const float* wr = w_tag + (size_t)tag*1024 + p*128;
        const float* hp = h + p*128;
        float s = 0.f;
        #pragma unroll 8
        for (int j = 0; j < 128; ++j) s += wr[j]*hp[j];
        partl[tid] = s;
    }
    __syncthreads();
    if (tid < NTAGS) {
        float s = b_tag[tid];
        #pragma unroll
        for (int p = 0; p < 8; ++p) s += partl[tid*8+p];
        feats[(size_t)t*NTAGS + tid] = s;
    }
}

// ---------------------------------------------------------------------------
// 4) Viterbi forward — ROUND 9 REBUILD. R8 ledger localized ~1.4ms here;
//    mechanism: the old 2x __syncthreads per step each forced
//    s_waitcnt vmcnt(0), draining the feats prefetch every step -> the
//    ~600-900cy cross-XCD feats load latency was fully exposed, 4096 times.
//    Fix: (a) block = 64 threads = exactly ONE wave -> barriers removed
//    entirely (same-wave LDS ordering is guaranteed by compiler-inserted
//    lgkmcnt; no barrier -> no vmcnt drain); (b) 8-deep register prefetch of
//    feats, fully unrolled so all indices are compile-time (rule #20);
//    (c) fvs broadcast via 6x ds_read_b128; (d) depth-5 tree argmax with
//    strict->-from-right combine = identical first-argmax semantics and
//    bit-identical values (max is order-independent; sc[p] expressions
//    unchanged). path_score arithmetic untouched -> bit-exact.
// ---------------------------------------------------------------------------
__global__ void viterbi_fwd_kernel(
    const float* __restrict__ feats, const float* __restrict__ trans,
    float* __restrict__ d_out, unsigned char* __restrict__ bp,
    int* __restrict__ best_tag)
{
    const int lane = threadIdx.x;       // 64 threads = 1 wave
    const bool act = lane < NTAGS;
    float tr[NTAGS];
    #pragma unroll
    for (int p = 0; p < NTAGS; ++p)
        tr[p] = act ? trans[lane*NTAGS + p] : NEGV;

    float fv = (lane == START_TAG) ? 0.f : NEGV;
    __shared__ __attribute__((aligned(16))) float fvs[NTAGS];
    __shared__ float term[NTAGS];

    // 8-deep register prefetch of feats (static indices via full unroll)
    float fpre[8];
    #pragma unroll
    for (int k = 0; k < 8; ++k)
        fpre[k] = act ? feats[(size_t)k*NTAGS + lane] : 0.f;

    for (int t0 = 0; t0 < T_SEQ; t0 += 8) {
        #pragma unroll
        for (int k = 0; k < 8; ++k) {
            const int t = t0 + k;
            const float ft = fpre[k];
            // refill slot k for t+8; consumed 8 steps from now (~8x the
            // per-step compute to cover cross-XCD L2 latency)
            if (act && t + 8 < T_SEQ)
                fpre[k] = feats[(size_t)(t + 8)*NTAGS + lane];

            if (act) fvs[lane] = fv;
            // no barrier: single wave; lgkmcnt orders the write vs reads.
            float fp[24];
            #pragma unroll
            for (int v = 0; v < 6; ++v)
                *(float4*)&fp[v*4] = *(const float4*)&fvs[v*4];

            float sc[24];
            #pragma unroll
            for (int p = 0; p < NTAGS; ++p) sc[p] = tr[p] + fp[p];

            // depth-5 first-argmax tree: right replaces left only if
            // STRICTLY greater -> same result as linear first-argmax scan.
            float v12[12]; int i12[12];
            #pragma unroll
            for (int p = 0; p < 12; ++p) {
                const bool g2 = sc[2*p+1] > sc[2*p];
                v12[p] = g2 ? sc[2*p+1] : sc[2*p];
                i12[p] = g2 ? (2*p+1) : (2*p);
            }
            float v6[6]; int i6[6];
            #pragma unroll
            for (int p = 0; p < 6; ++p) {
                const bool g2 = v12[2*p+1] > v12[2*p];
                v6[p] = g2 ? v12[2*p+1] : v12[2*p];
                i6[p] = g2 ? i12[2*p+1] : i12[2*p];
            }
            float v3[3]; int i3[3];
            #pragma unroll
            for (int p = 0; p < 3; ++p) {
                const bool g2 = v6[2*p+1] > v6[2*p];
                v3[p] = g2 ? v6[2*p+1] : v6[2*p];
                i3[p] = g2 ? i6[2*p+1] : i6[2*p];
            }
            float bv01 = (v3[1] > v3[0]) ? v3[1] : v3[0];
            int   bi01 = (v3[1] > v3[0]) ? i3[1] : i3[0];
            const float bestv = (v3[2] > bv01) ? v3[2] : bv01;
            const int   argp  = (v3[2] > bv01) ? i3[2] : bi01;

            fv = bestv + ft;
            if (act) bp[(size_t)t*NTAGS + lane] = (unsigned char)argp;
        }
    }
    if (act) { fv += trans[STOP_TAG*NTAGS + lane]; term[lane] = fv; }
    // single wave: term writes ordered before lane0's reads via lgkmcnt
    if (lane == 0) {
        float bv = term[0]; int bi = 0;
        #pragma unroll
        for (int p = 1; p < NTAGS; ++p) if (term[p] > bv) { bv = term[p]; bi = p; }
        d_out[0] = bv;
        *best_tag = bi;
    }
}

// ---------------------------------------------------------------------------
// 5) Hierarchical backtrack
// ---------------------------------------------------------------------------
__global__ void bt_compose_kernel(const unsigned char* __restrict__ bp,
                                  unsigned char* __restrict__ segmap)
{
    const int s = blockIdx.x;
    const int tid = threadIdx.x;   // 64
    __shared__ __attribute__((aligned(16))) unsigned char lbp[64*NTAGS];
    const uint32_t* src = (const uint32_t*)(bp + (size_t)s * 64 * NTAGS);
    uint32_t* dst = (uint32_t*)lbp;
    #pragma unroll
    for (int i = 0; i < 6; ++i) dst[tid + 64*i] = src[tid + 64*i];
    __syncthreads();
    if (tid < NTAGS) {
        int m = tid;
        for (int tt = 63; tt >= 0; --tt) m = lbp[tt*NTAGS + m];
        segmap[s*NTAGS + tid] = (unsigned char)m;
    }
}

__global__ void bt_final_kernel(const unsigned char* __restrict__ segmap,
                                const int* __restrict__ best_tag,
                                int* __restrict__ end_tags)
{
    if (threadIdx.x == 0) {
        int tag = *best_tag;
        end_tags[63] = tag;
        for (int s = 63; s >= 1; --s) {
            tag = segmap[s*NTAGS + tag];
            end_tags[s-1] = tag;
        }
    }
}

__global__ void bt_write_kernel(const unsigned char* __restrict__ bp,
                                const int* __restrict__ end_tags,
                                float* __restrict__ out_path)
{
    const int s = blockIdx.x;
    const int tid = threadIdx.x;   // 64
    __shared__ __attribute__((aligned(16))) unsigned char lbp[64*NTAGS];
    const uint32_t* src = (const uint32_t*)(bp + (size_t)s * 64 * NTAGS);
    uint32_t* dst = (uint32_t*)lbp;
    #pragma unroll
    for (int i = 0; i < 6; ++i) dst[tid + 64*i] = src[tid + 64*i];
    __syncthreads();
    if (tid == 0) {
        int tag = end_tags[s];
        out_path[s*64 + 63] = (float)tag;
        for (int tt = 63; tt >= 1; --tt) {
            tag = lbp[tt*NTAGS + tag];
            out_path[s*64 + tt - 1] = (float)tag;
        }
    }
}

// ---------------------------------------------------------------------------
extern "C" void kernel_launch(void* const* d_in, const int* in_sizes, int n_in,
                              void* d_out, int out_size, void* d_ws, size_t ws_size,
                              hipStream_t stream)
{
    const int*   sent   = (const int*)d_in[0];
    const float* emb    = (const float*)d_in[1];
    const float* w_ih_f = (const float*)d_in[2];
    const float* w_hh_f = (const float*)d_in[3];
    const float* b_ih_f = (const float*)d_in[4];
    const float* b_hh_f = (const float*)d_in[5];
    const float* w_ih_b = (const float*)d_in[6];
    const float* w_hh_b = (const float*)d_in[7];
    const float* b_ih_b = (const float*)d_in[8];
    const float* b_hh_b = (const float*)d_in[9];
    const float* w_tag  = (const float*)d_in[10];
    const float* b_tag  = (const float*)d_in[11];
    const float* trans  = (const float*)d_in[12];
    const float* h0     = (const float*)d_in[13];
    const float* c0     = (const float*)d_in[14];
    float* out = (float*)d_out;

    char* ws = (char*)d_ws;
    size_t off = 0;
    auto alloc = [&](size_t bytes) {
        char* p = ws + off; off += (bytes + 255) & ~(size_t)255; return p;
    };
    float* xg      = (float*)alloc((size_t)2*T_SEQ*G4*sizeof(float));      // 64 MB
    uint32_t* h_hist = (uint32_t*)alloc((size_t)2*T_SEQ*HDIM*sizeof(float)); // 16 MB
    float* feats   = (float*)alloc((size_t)T_SEQ*NTAGS*sizeof(float));
    unsigned char* bp     = (unsigned char*)alloc((size_t)T_SEQ*NTAGS);
    unsigned char* segmap = (unsigned char*)alloc(64*NTAGS);
    int* best_tag = (int*)alloc(sizeof(int));
    int* end_tags = (int*)alloc(64*sizeof(int));
    int* claim    = (int*)alloc(8*sizeof(int));

    if (off > ws_size) {   // diagnostic sentinel: workspace too small
        hipMemsetAsync(d_out, 0xFF, 4, stream);
        return;
    }

    // h_hist = 0xFFFFFFFF sentinel (data-is-the-flag; harness poison is 0xAA)
    hipMemsetAsync(h_hist, 0xFF, (size_t)2*T_SEQ*HDIM*sizeof(float), stream);
    hipMemsetAsync(claim, 0, 8*sizeof(int), stream);

    dim3 gg(G4/64, T_SEQ/64, 2);
    gemm_xg_kernel<<<gg, 256, 0, stream>>>(sent, emb,
        w_ih_f, b_ih_f, b_hh_f, w_ih_b, b_ih_b, b_hh_b, xg);
    bilstm_kernel<<<512, 512, 0, stream>>>(w_hh_f, w_hh_b, h0, c0, xg, h_hist, claim);
    feats_kernel<<<T_SEQ, 256, 0, stream>>>((const float*)h_hist, w_tag, b_tag, feats);
    viterbi_fwd_kernel<<<1, 64, 0, stream>>>(feats, trans, out, bp, best_tag);
    bt_compose_kernel<<<64, 64, 0, stream>>>(bp, segmap);
    bt_final_kernel<<<1, 64, 0, stream>>>(segmap, best_tag, end_tags);
    bt_write_kernel<<<64, 64, 0, stream>>>(bp, end_tags, out + 1);
}